// Round 5
// baseline (1673.395 us; speedup 1.0000x reference)
//
#include <hip/hip_runtime.h>
#include <hip/hip_bf16.h>
#include <math.h>

#define SLOPE 0.2f

static inline int imin(int a, int b) { return a < b ? a : b; }

// ---------------- GEMM + attention dots ----------------
template<int HC>
__global__ __launch_bounds__(256, 2)
void gemm_att(const float* __restrict__ x, const float* __restrict__ W,
              const float* __restrict__ att_s, const float* __restrict__ att_d,
              float* __restrict__ h, float* __restrict__ a_s, float* __restrict__ a_d,
              int N) {
    constexpr int CG = HC / 4;
    constexpr int RSLOTS = 256 / CG;
    constexpr int R = 4;
    constexpr int ROWS = RSLOTS * R;
    constexpr int H = HC / 64;
    constexpr int XS = (HC == 128) ? 128 : 132;

    __shared__ float4 W_lds[128 * CG];
    __shared__ float x_lds[ROWS * XS];

    const int tid = threadIdx.x;
    const int cg = tid % CG;
    const int rslot = tid / CG;

    for (int i = tid; i < 128 * CG; i += 256)
        W_lds[i] = ((const float4*)W)[i];

    const float4 asv = ((const float4*)att_s)[cg];
    const float4 adv = ((const float4*)att_d)[cg];

    const int ntiles = (N + ROWS - 1) / ROWS;
    for (int t = blockIdx.x; t < ntiles; t += gridDim.x) {
        const int row0 = t * ROWS;
        __syncthreads();
        for (int i = tid; i < ROWS * 32; i += 256) {
            int r = i >> 5, k4 = i & 31;
            int row = row0 + r;
            float4 v = (row < N) ? ((const float4*)x)[(size_t)row * 32 + k4]
                                 : make_float4(0.f, 0.f, 0.f, 0.f);
            *(float4*)&x_lds[r * XS + k4 * 4] = v;
        }
        __syncthreads();

        float4 acc[R];
#pragma unroll
        for (int r = 0; r < R; ++r) acc[r] = make_float4(0.f, 0.f, 0.f, 0.f);

#pragma unroll 4
        for (int k = 0; k < 128; ++k) {
            float4 w = W_lds[k * CG + cg];
#pragma unroll
            for (int r = 0; r < R; ++r) {
                float xv = x_lds[(rslot * R + r) * XS + k];
                acc[r].x = fmaf(xv, w.x, acc[r].x);
                acc[r].y = fmaf(xv, w.y, acc[r].y);
                acc[r].z = fmaf(xv, w.z, acc[r].z);
                acc[r].w = fmaf(xv, w.w, acc[r].w);
            }
        }

#pragma unroll
        for (int r = 0; r < R; ++r) {
            int row = row0 + rslot * R + r;
            if (row < N) {
                ((float4*)h)[(size_t)row * CG + cg] = acc[r];
                float vs = acc[r].x * asv.x + acc[r].y * asv.y
                         + acc[r].z * asv.z + acc[r].w * asv.w;
                float vd = acc[r].x * adv.x + acc[r].y * adv.y
                         + acc[r].z * adv.z + acc[r].w * adv.w;
#pragma unroll
                for (int off = 1; off < 16; off <<= 1) {
                    vs += __shfl_xor(vs, off);
                    vd += __shfl_xor(vd, off);
                }
                if ((tid & 15) == 0) {
                    int head = (H == 2) ? ((tid >> 4) & 1) : 0;
                    a_s[row * H + head] = vs;
                    a_d[row * H + head] = vd;
                }
            }
        }
    }
}

// ---------------- CSR build via 2-level counting sort (bucket = dst>>8) ----
__global__ __launch_bounds__(256)
void bhist_k(const int* __restrict__ ei, int E, int Etot, int* __restrict__ bcnt) {
    int i = blockIdx.x * 256 + threadIdx.x, st = gridDim.x * 256;
    for (int e = i; e < Etot; e += st) {
        int dst = (e < E) ? ei[E + e] : (e - E);
        atomicAdd(&bcnt[dst >> 8], 1);
    }
}

// single block: exclusive scan of nb (<=512) bucket counts
__global__ __launch_bounds__(512)
void bscan_k(const int* __restrict__ bcnt, int* __restrict__ bbase,
             int* __restrict__ bnext, int* __restrict__ rowptr,
             int nb, int N, int Etot) {
    __shared__ int sm[512];
    int t = threadIdx.x;
    int v = (t < nb) ? bcnt[t] : 0;
    sm[t] = v; __syncthreads();
    for (int off = 1; off < 512; off <<= 1) {
        int u = (t >= off) ? sm[t - off] : 0;
        __syncthreads();
        sm[t] += u;
        __syncthreads();
    }
    if (t < nb) {
        int excl = sm[t] - v;
        bbase[t] = excl;
        bnext[t] = excl;
    }
    if (t == 0) {
        bbase[nb] = Etot;
        rowptr[N] = Etot;
    }
}

// scatter edges into bucket-sorted pair array; writes per bucket are
// near-sequential so cache lines fill completely (no write amplification)
__global__ __launch_bounds__(256)
void bscatter_k(const int* __restrict__ ei, int E, int Etot,
                int* __restrict__ bnext, unsigned long long* __restrict__ pairs) {
    int i = blockIdx.x * 256 + threadIdx.x, st = gridDim.x * 256;
    for (int e = i; e < Etot; e += st) {
        int src = (e < E) ? ei[e] : (e - E);
        int dst = (e < E) ? ei[E + e] : (e - E);
        int p = atomicAdd(&bnext[dst >> 8], 1);
        pairs[p] = ((unsigned long long)(unsigned)dst << 32) | (unsigned)src;
    }
}

// one block per bucket: LDS histogram over the bucket's 256 nodes -> LDS scan
// -> rowptr + in-bucket placement (colsrc writes stay in a ~17KB window)
__global__ __launch_bounds__(256)
void fine_k(const unsigned long long* __restrict__ pairs,
            const int* __restrict__ bbase, int* __restrict__ rowptr,
            int* __restrict__ colsrc, int N) {
    __shared__ int sm[256];
    __shared__ int lnext[256];
    const int b = blockIdx.x, t = threadIdx.x;
    const int beg = bbase[b], end = bbase[b + 1];

    lnext[t] = 0;   // use as lcnt first
    __syncthreads();
    for (int i = beg + t; i < end; i += 256)
        atomicAdd(&lnext[(int)(pairs[i] >> 32) & 255], 1);
    __syncthreads();
    int v = lnext[t];
    sm[t] = v; __syncthreads();
    for (int off = 1; off < 256; off <<= 1) {
        int u = (t >= off) ? sm[t - off] : 0;
        __syncthreads();
        sm[t] += u;
        __syncthreads();
    }
    int excl = sm[t] - v;
    int node = (b << 8) + t;
    if (node < N) rowptr[node] = beg + excl;
    lnext[t] = excl;
    __syncthreads();
    for (int i = beg + t; i < end; i += 256) {
        unsigned long long pr = pairs[i];
        int dst = (int)(pr >> 32);
        int src = (int)(pr & 0xffffffffu);
        int p = atomicAdd(&lnext[dst & 255], 1);
        colsrc[beg + p] = src;
    }
}

// ---------------- fused per-node aggregation, single-pass online softmax ----
template<int H, bool ELU>
__global__ __launch_bounds__(256)
void node_aggr(const int* __restrict__ rowptr, const int* __restrict__ colsrc,
               const float* __restrict__ a_s, const float* __restrict__ a_d,
               const float* __restrict__ h, const float* __restrict__ bias,
               float* __restrict__ out, int N) {
    int gw = (blockIdx.x * 256 + threadIdx.x) >> 6;
    int lane = threadIdx.x & 63;
    int nw = (gridDim.x * 256) >> 6;

    for (int n = gw; n < N; n += nw) {
        const int b = rowptr[n], deg = rowptr[n + 1] - b;

        if (H == 2) {
            const float2 adn = ((const float2*)a_d)[n];
            float m0 = -INFINITY, m1 = -INFINITY;
            float accx = 0.f, accy = 0.f, den = 0.f;
            for (int c = 0; c < deg; c += 64) {
                int ii = c + lane;
                int src_r = 0;
                float s0_r = -INFINITY, s1_r = -INFINITY;
                if (ii < deg) {
                    src_r = colsrc[b + ii];
                    float2 as = ((const float2*)a_s)[src_r];
                    s0_r = as.x + adn.x; s0_r = s0_r > 0.f ? s0_r : SLOPE * s0_r;
                    s1_r = as.y + adn.y; s1_r = s1_r > 0.f ? s1_r : SLOPE * s1_r;
                }
                float c0 = s0_r, c1 = s1_r;
#pragma unroll
                for (int off = 32; off; off >>= 1) {
                    c0 = fmaxf(c0, __shfl_xor(c0, off));
                    c1 = fmaxf(c1, __shfl_xor(c1, off));
                }
                float nm0 = fmaxf(m0, c0), nm1 = fmaxf(m1, c1);
                if (c > 0) {
                    float sc = (lane < 32) ? __expf(m0 - nm0) : __expf(m1 - nm1);
                    accx *= sc; accy *= sc; den *= sc;
                }
                m0 = nm0; m1 = nm1;
                float w0_r = __expf(s0_r - m0);
                float w1_r = __expf(s1_r - m1);
                int lim = (deg - c < 64) ? (deg - c) : 64;
#pragma unroll 2
                for (int i = 0; i < lim; ++i) {
                    int src = __shfl(src_r, i);
                    float w0b = __shfl(w0_r, i);
                    float w1b = __shfl(w1_r, i);
                    float w = (lane < 32) ? w0b : w1b;
                    den += w;
                    float2 hv = ((const float2*)h)[(size_t)src * 64 + lane];
                    accx = fmaf(w, hv.x, accx);
                    accy = fmaf(w, hv.y, accy);
                }
            }
            float2 bv = ((const float2*)bias)[lane];
            float vx = accx / den + bv.x;
            float vy = accy / den + bv.y;
            if (ELU) {
                vx = vx > 0.f ? vx : expm1f(vx);
                vy = vy > 0.f ? vy : expm1f(vy);
            }
            ((float2*)out)[(size_t)n * 64 + lane] = make_float2(vx, vy);
        } else {
            const float adn = a_d[n];
            float m = -INFINITY, acc = 0.f, den = 0.f;
            for (int c = 0; c < deg; c += 64) {
                int ii = c + lane;
                int src_r = 0;
                float s_r = -INFINITY;
                if (ii < deg) {
                    src_r = colsrc[b + ii];
                    s_r = a_s[src_r] + adn;
                    s_r = s_r > 0.f ? s_r : SLOPE * s_r;
                }
                float cm = s_r;
#pragma unroll
                for (int off = 32; off; off >>= 1) cm = fmaxf(cm, __shfl_xor(cm, off));
                float nm = fmaxf(m, cm);
                if (c > 0) {
                    float sc = __expf(m - nm);
                    acc *= sc; den *= sc;
                }
                m = nm;
                float w_r = __expf(s_r - m);
                int lim = (deg - c < 64) ? (deg - c) : 64;
#pragma unroll 2
                for (int i = 0; i < lim; ++i) {
                    int src = __shfl(src_r, i);
                    float w = __shfl(w_r, i);
                    den += w;
                    acc = fmaf(w, h[(size_t)src * 64 + lane], acc);
                }
            }
            float v = acc / den + bias[lane];
            if (ELU) v = v > 0.f ? v : expm1f(v);
            out[(size_t)n * 64 + lane] = v;
        }
    }
}

extern "C" void kernel_launch(void* const* d_in, const int* in_sizes, int n_in,
                              void* d_out, int out_size, void* d_ws, size_t ws_size,
                              hipStream_t stream) {
    const float* x   = (const float*)d_in[0];
    const int*   ei  = (const int*)d_in[1];
    const float* W1  = (const float*)d_in[2];
    const float* as1 = (const float*)d_in[3];
    const float* ad1 = (const float*)d_in[4];
    const float* b1  = (const float*)d_in[5];
    const float* W2  = (const float*)d_in[6];
    const float* as2 = (const float*)d_in[7];
    const float* ad2 = (const float*)d_in[8];
    const float* b2  = (const float*)d_in[9];
    float* out = (float*)d_out;

    const int N = out_size / 64;          // 100000
    const int E = in_sizes[1] / 2;        // 1600000
    const int Etot = E + N;               // + self loops
    const int nb = (N + 255) >> 8;        // buckets (391 <= 512)

    // workspace:
    // floats: h1 [128N] | h1e [128N] | a_s1 [2N] | a_d1 [2N] | a_s2 [N] | a_d2 [N]
    // ints:   rowptr [N+1] | bcnt [512] | bbase [513] | bnext [512] | colsrc [Etot]
    // pairs (u64 x Etot) aliases h1 (dead until gemm_att<128> runs, after CSR)
    float* ws   = (float*)d_ws;
    float* h1   = ws;
    float* h1e  = ws + (size_t)N * 128;
    float* a_s1 = h1e + (size_t)N * 128;
    float* a_d1 = a_s1 + (size_t)N * 2;
    float* a_s2 = a_d1 + (size_t)N * 2;
    float* a_d2 = a_s2 + (size_t)N;
    int* rowptr = (int*)(a_d2 + (size_t)N);
    int* bcnt   = rowptr + (N + 1);
    int* bbase  = bcnt + 512;
    int* bnext  = bbase + 513;
    int* colsrc = bnext + 512;
    unsigned long long* pairs = (unsigned long long*)h1;

    // ---- CSR build (shared by both layers) ----
    hipMemsetAsync(bcnt, 0, (size_t)nb * 4, stream);
    int eb = imin((Etot + 255) / 256, 4096);
    bhist_k<<<dim3(eb), dim3(256), 0, stream>>>(ei, E, Etot, bcnt);
    bscan_k<<<dim3(1), dim3(512), 0, stream>>>(bcnt, bbase, bnext, rowptr, nb, N, Etot);
    bscatter_k<<<dim3(eb), dim3(256), 0, stream>>>(ei, E, Etot, bnext, pairs);
    fine_k<<<dim3(nb), dim3(256), 0, stream>>>(pairs, bbase, rowptr, colsrc, N);

    int ab = imin((N + 3) / 4, 25000);

    // ---- layer 1 ----
    gemm_att<128><<<dim3(1024), dim3(256), 0, stream>>>(
        x, W1, as1, ad1, h1, a_s1, a_d1, N);
    node_aggr<2, true><<<dim3(ab), dim3(256), 0, stream>>>(
        rowptr, colsrc, a_s1, a_d1, h1, b1, h1e, N);

    // ---- layer 2 ----
    float* h2 = h1;   // h1 dead after node_aggr<2>
    gemm_att<64><<<dim3(1024), dim3(256), 0, stream>>>(
        h1e, W2, as2, ad2, h2, a_s2, a_d2, N);
    node_aggr<1, false><<<dim3(ab), dim3(256), 0, stream>>>(
        rowptr, colsrc, a_s2, a_d2, h2, b2, out, N);
}

// Round 7
// 423.134 us; speedup vs baseline: 3.9548x; 3.9548x over previous
//
#include <hip/hip_runtime.h>
#include <hip/hip_bf16.h>
#include <math.h>

#define SLOPE 0.2f
#define CHUNK 4096

__host__ __device__ static inline int imin(int a, int b) { return a < b ? a : b; }

// ---------------- GEMM + attention dots ----------------
template<int HC>
__global__ __launch_bounds__(256, 2)
void gemm_att(const float* __restrict__ x, const float* __restrict__ W,
              const float* __restrict__ att_s, const float* __restrict__ att_d,
              float* __restrict__ h, float* __restrict__ a_s, float* __restrict__ a_d,
              int N) {
    constexpr int CG = HC / 4;
    constexpr int RSLOTS = 256 / CG;
    constexpr int R = 4;
    constexpr int ROWS = RSLOTS * R;
    constexpr int H = HC / 64;
    constexpr int XS = (HC == 128) ? 128 : 132;

    __shared__ float4 W_lds[128 * CG];
    __shared__ float x_lds[ROWS * XS];

    const int tid = threadIdx.x;
    const int cg = tid % CG;
    const int rslot = tid / CG;

    for (int i = tid; i < 128 * CG; i += 256)
        W_lds[i] = ((const float4*)W)[i];

    const float4 asv = ((const float4*)att_s)[cg];
    const float4 adv = ((const float4*)att_d)[cg];

    const int ntiles = (N + ROWS - 1) / ROWS;
    for (int t = blockIdx.x; t < ntiles; t += gridDim.x) {
        const int row0 = t * ROWS;
        __syncthreads();
        for (int i = tid; i < ROWS * 32; i += 256) {
            int r = i >> 5, k4 = i & 31;
            int row = row0 + r;
            float4 v = (row < N) ? ((const float4*)x)[(size_t)row * 32 + k4]
                                 : make_float4(0.f, 0.f, 0.f, 0.f);
            *(float4*)&x_lds[r * XS + k4 * 4] = v;
        }
        __syncthreads();

        float4 acc[R];
#pragma unroll
        for (int r = 0; r < R; ++r) acc[r] = make_float4(0.f, 0.f, 0.f, 0.f);

#pragma unroll 4
        for (int k = 0; k < 128; ++k) {
            float4 w = W_lds[k * CG + cg];
#pragma unroll
            for (int r = 0; r < R; ++r) {
                float xv = x_lds[(rslot * R + r) * XS + k];
                acc[r].x = fmaf(xv, w.x, acc[r].x);
                acc[r].y = fmaf(xv, w.y, acc[r].y);
                acc[r].z = fmaf(xv, w.z, acc[r].z);
                acc[r].w = fmaf(xv, w.w, acc[r].w);
            }
        }

#pragma unroll
        for (int r = 0; r < R; ++r) {
            int row = row0 + rslot * R + r;
            if (row < N) {
                ((float4*)h)[(size_t)row * CG + cg] = acc[r];
                float vs = acc[r].x * asv.x + acc[r].y * asv.y
                         + acc[r].z * asv.z + acc[r].w * asv.w;
                float vd = acc[r].x * adv.x + acc[r].y * adv.y
                         + acc[r].z * adv.z + acc[r].w * adv.w;
#pragma unroll
                for (int off = 1; off < 16; off <<= 1) {
                    vs += __shfl_xor(vs, off);
                    vd += __shfl_xor(vd, off);
                }
                if ((tid & 15) == 0) {
                    int head = (H == 2) ? ((tid >> 4) & 1) : 0;
                    a_s[row * H + head] = vs;
                    a_d[row * H + head] = vd;
                }
            }
        }
    }
}

// ---------------- CSR build via 2-level counting sort (bucket = dst>>8) ----
// Privatized: per-block LDS histogram, then ONE global atomic per (block,bucket).
__global__ __launch_bounds__(256)
void bhist_k(const int* __restrict__ ei, int E, int Etot,
             int* __restrict__ bcnt, int nb) {
    __shared__ int lcnt[512];
    const int t = threadIdx.x;
    for (int i = t; i < nb; i += 256) lcnt[i] = 0;
    __syncthreads();
    const int c0 = blockIdx.x * CHUNK;
    const int lim = imin(CHUNK, Etot - c0);
    for (int j = t; j < lim; j += 256) {
        int e = c0 + j;
        int dst = (e < E) ? ei[E + e] : (e - E);
        atomicAdd(&lcnt[dst >> 8], 1);
    }
    __syncthreads();
    for (int i = t; i < nb; i += 256)
        if (lcnt[i]) atomicAdd(&bcnt[i], lcnt[i]);
}

// single block: exclusive scan of nb (<=512) bucket counts
__global__ __launch_bounds__(512)
void bscan_k(const int* __restrict__ bcnt, int* __restrict__ bbase,
             int* __restrict__ bnext, int* __restrict__ rowptr,
             int nb, int N, int Etot) {
    __shared__ int sm[512];
    int t = threadIdx.x;
    int v = (t < nb) ? bcnt[t] : 0;
    sm[t] = v; __syncthreads();
    for (int off = 1; off < 512; off <<= 1) {
        int u = (t >= off) ? sm[t - off] : 0;
        __syncthreads();
        sm[t] += u;
        __syncthreads();
    }
    if (t < nb) {
        int excl = sm[t] - v;
        bbase[t] = excl;
        bnext[t] = excl;
    }
    if (t == 0) {
        bbase[nb] = Etot;
        rowptr[N] = Etot;
    }
}

// privatized scatter: LDS histogram of the chunk -> bulk-reserve window per
// bucket (1 global atomic each) -> write pairs via LDS cursors
__global__ __launch_bounds__(256)
void bscatter_k(const int* __restrict__ ei, int E, int Etot,
                int* __restrict__ bnext, unsigned long long* __restrict__ pairs,
                int nb) {
    __shared__ int lcnt[512];
    __shared__ int lbase[512];
    const int t = threadIdx.x;
    const int c0 = blockIdx.x * CHUNK;
    const int lim = imin(CHUNK, Etot - c0);

    for (int i = t; i < nb; i += 256) lcnt[i] = 0;
    __syncthreads();
    for (int j = t; j < lim; j += 256) {
        int e = c0 + j;
        int dst = (e < E) ? ei[E + e] : (e - E);
        atomicAdd(&lcnt[dst >> 8], 1);
    }
    __syncthreads();
    for (int i = t; i < nb; i += 256) {
        int c = lcnt[i];
        lbase[i] = c ? atomicAdd(&bnext[i], c) : 0;
        lcnt[i] = 0;   // reuse as cursor
    }
    __syncthreads();
    for (int j = t; j < lim; j += 256) {
        int e = c0 + j;
        int src = (e < E) ? ei[e] : (e - E);
        int dst = (e < E) ? ei[E + e] : (e - E);
        int b = dst >> 8;
        int off = atomicAdd(&lcnt[b], 1);
        pairs[lbase[b] + off] = ((unsigned long long)(unsigned)dst << 32) | (unsigned)src;
    }
}

// one block per bucket: LDS histogram over the bucket's 256 nodes -> LDS scan
// -> rowptr + in-bucket placement (colsrc writes stay in a ~17KB window)
__global__ __launch_bounds__(256)
void fine_k(const unsigned long long* __restrict__ pairs,
            const int* __restrict__ bbase, int* __restrict__ rowptr,
            int* __restrict__ colsrc, int N) {
    __shared__ int sm[256];
    __shared__ int lnext[256];
    const int b = blockIdx.x, t = threadIdx.x;
    const int beg = bbase[b], end = bbase[b + 1];

    lnext[t] = 0;
    __syncthreads();
    for (int i = beg + t; i < end; i += 256)
        atomicAdd(&lnext[(int)(pairs[i] >> 32) & 255], 1);
    __syncthreads();
    int v = lnext[t];
    sm[t] = v; __syncthreads();
    for (int off = 1; off < 256; off <<= 1) {
        int u = (t >= off) ? sm[t - off] : 0;
        __syncthreads();
        sm[t] += u;
        __syncthreads();
    }
    int excl = sm[t] - v;
    int node = (b << 8) + t;
    if (node < N) rowptr[node] = beg + excl;
    lnext[t] = excl;
    __syncthreads();
    for (int i = beg + t; i < end; i += 256) {
        unsigned long long pr = pairs[i];
        int dst = (int)(pr >> 32);
        int src = (int)(pr & 0xffffffffu);
        int p = atomicAdd(&lnext[dst & 255], 1);
        colsrc[beg + p] = src;
    }
}

// ---------------- fused per-node aggregation, single-pass online softmax ----
template<int H, bool ELU>
__global__ __launch_bounds__(256)
void node_aggr(const int* __restrict__ rowptr, const int* __restrict__ colsrc,
               const float* __restrict__ a_s, const float* __restrict__ a_d,
               const float* __restrict__ h, const float* __restrict__ bias,
               float* __restrict__ out, int N) {
    int gw = (blockIdx.x * 256 + threadIdx.x) >> 6;
    int lane = threadIdx.x & 63;
    int nw = (gridDim.x * 256) >> 6;

    for (int n = gw; n < N; n += nw) {
        const int b = rowptr[n], deg = rowptr[n + 1] - b;

        if (H == 2) {
            const float2 adn = ((const float2*)a_d)[n];
            float m0 = -INFINITY, m1 = -INFINITY;
            float accx = 0.f, accy = 0.f, den = 0.f;
            for (int c = 0; c < deg; c += 64) {
                int ii = c + lane;
                int src_r = 0;
                float s0_r = -INFINITY, s1_r = -INFINITY;
                if (ii < deg) {
                    src_r = colsrc[b + ii];
                    float2 as = ((const float2*)a_s)[src_r];
                    s0_r = as.x + adn.x; s0_r = s0_r > 0.f ? s0_r : SLOPE * s0_r;
                    s1_r = as.y + adn.y; s1_r = s1_r > 0.f ? s1_r : SLOPE * s1_r;
                }
                float c0 = s0_r, c1 = s1_r;
#pragma unroll
                for (int off = 32; off; off >>= 1) {
                    c0 = fmaxf(c0, __shfl_xor(c0, off));
                    c1 = fmaxf(c1, __shfl_xor(c1, off));
                }
                float nm0 = fmaxf(m0, c0), nm1 = fmaxf(m1, c1);
                if (c > 0) {
                    float sc = (lane < 32) ? __expf(m0 - nm0) : __expf(m1 - nm1);
                    accx *= sc; accy *= sc; den *= sc;
                }
                m0 = nm0; m1 = nm1;
                float w0_r = __expf(s0_r - m0);
                float w1_r = __expf(s1_r - m1);
                int lim = (deg - c < 64) ? (deg - c) : 64;
#pragma unroll 2
                for (int i = 0; i < lim; ++i) {
                    int src = __shfl(src_r, i);
                    float w0b = __shfl(w0_r, i);
                    float w1b = __shfl(w1_r, i);
                    float w = (lane < 32) ? w0b : w1b;
                    den += w;
                    float2 hv = ((const float2*)h)[(size_t)src * 64 + lane];
                    accx = fmaf(w, hv.x, accx);
                    accy = fmaf(w, hv.y, accy);
                }
            }
            float2 bv = ((const float2*)bias)[lane];
            float vx = accx / den + bv.x;
            float vy = accy / den + bv.y;
            if (ELU) {
                vx = vx > 0.f ? vx : expm1f(vx);
                vy = vy > 0.f ? vy : expm1f(vy);
            }
            ((float2*)out)[(size_t)n * 64 + lane] = make_float2(vx, vy);
        } else {
            const float adn = a_d[n];
            float m = -INFINITY, acc = 0.f, den = 0.f;
            for (int c = 0; c < deg; c += 64) {
                int ii = c + lane;
                int src_r = 0;
                float s_r = -INFINITY;
                if (ii < deg) {
                    src_r = colsrc[b + ii];
                    s_r = a_s[src_r] + adn;
                    s_r = s_r > 0.f ? s_r : SLOPE * s_r;
                }
                float cm = s_r;
#pragma unroll
                for (int off = 32; off; off >>= 1) cm = fmaxf(cm, __shfl_xor(cm, off));
                float nm = fmaxf(m, cm);
                if (c > 0) {
                    float sc = __expf(m - nm);
                    acc *= sc; den *= sc;
                }
                m = nm;
                float w_r = __expf(s_r - m);
                int lim = (deg - c < 64) ? (deg - c) : 64;
#pragma unroll 2
                for (int i = 0; i < lim; ++i) {
                    int src = __shfl(src_r, i);
                    float w = __shfl(w_r, i);
                    den += w;
                    acc = fmaf(w, h[(size_t)src * 64 + lane], acc);
                }
            }
            float v = acc / den + bias[lane];
            if (ELU) v = v > 0.f ? v : expm1f(v);
            out[(size_t)n * 64 + lane] = v;
        }
    }
}

extern "C" void kernel_launch(void* const* d_in, const int* in_sizes, int n_in,
                              void* d_out, int out_size, void* d_ws, size_t ws_size,
                              hipStream_t stream) {
    const float* x   = (const float*)d_in[0];
    const int*   ei  = (const int*)d_in[1];
    const float* W1  = (const float*)d_in[2];
    const float* as1 = (const float*)d_in[3];
    const float* ad1 = (const float*)d_in[4];
    const float* b1  = (const float*)d_in[5];
    const float* W2  = (const float*)d_in[6];
    const float* as2 = (const float*)d_in[7];
    const float* ad2 = (const float*)d_in[8];
    const float* b2  = (const float*)d_in[9];
    float* out = (float*)d_out;

    const int N = out_size / 64;          // 100000
    const int E = in_sizes[1] / 2;        // 1600000
    const int Etot = E + N;               // + self loops
    const int nb = (N + 255) >> 8;        // buckets (391 <= 512)

    float* ws   = (float*)d_ws;
    float* h1   = ws;
    float* h1e  = ws + (size_t)N * 128;
    float* a_s1 = h1e + (size_t)N * 128;
    float* a_d1 = a_s1 + (size_t)N * 2;
    float* a_s2 = a_d1 + (size_t)N * 2;
    float* a_d2 = a_s2 + (size_t)N;
    int* rowptr = (int*)(a_d2 + (size_t)N);
    int* bcnt   = rowptr + (N + 1);
    int* bbase  = bcnt + 512;
    int* bnext  = bbase + 513;
    int* colsrc = bnext + 512;
    unsigned long long* pairs = (unsigned long long*)h1;   // dead until gemm

    // ---- CSR build (shared by both layers) ----
    (void)hipMemsetAsync(bcnt, 0, (size_t)nb * 4, stream);
    int cb = (Etot + CHUNK - 1) / CHUNK;        // 416 chunks
    bhist_k<<<dim3(cb), dim3(256), 0, stream>>>(ei, E, Etot, bcnt, nb);
    bscan_k<<<dim3(1), dim3(512), 0, stream>>>(bcnt, bbase, bnext, rowptr, nb, N, Etot);
    bscatter_k<<<dim3(cb), dim3(256), 0, stream>>>(ei, E, Etot, bnext, pairs, nb);
    fine_k<<<dim3(nb), dim3(256), 0, stream>>>(pairs, bbase, rowptr, colsrc, N);

    int ab = imin((N + 3) / 4, 25000);

    // ---- layer 1 ----
    gemm_att<128><<<dim3(1024), dim3(256), 0, stream>>>(
        x, W1, as1, ad1, h1, a_s1, a_d1, N);
    node_aggr<2, true><<<dim3(ab), dim3(256), 0, stream>>>(
        rowptr, colsrc, a_s1, a_d1, h1, b1, h1e, N);

    // ---- layer 2 ----
    float* h2 = h1;   // h1 dead after node_aggr<2>
    gemm_att<64><<<dim3(1024), dim3(256), 0, stream>>>(
        h1e, W2, as2, ad2, h2, a_s2, a_d2, N);
    node_aggr<1, false><<<dim3(ab), dim3(256), 0, stream>>>(
        rowptr, colsrc, a_s2, a_d2, h2, b2, out, N);
}

// Round 8
// 394.548 us; speedup vs baseline: 4.2413x; 1.0725x over previous
//
#include <hip/hip_runtime.h>
#include <hip/hip_bf16.h>
#include <hip/hip_fp16.h>
#include <math.h>

#define SLOPE 0.2f
#define CHUNK 4096

__host__ __device__ static inline int imin(int a, int b) { return a < b ? a : b; }

// ---------------- GEMM + attention dots; h written as fp16 ----------------
template<int HC>
__global__ __launch_bounds__(256, 2)
void gemm_att(const float* __restrict__ x, const float* __restrict__ W,
              const float* __restrict__ att_s, const float* __restrict__ att_d,
              __half* __restrict__ h, float* __restrict__ a_s, float* __restrict__ a_d,
              int N) {
    constexpr int CG = HC / 4;
    constexpr int RSLOTS = 256 / CG;
    constexpr int R = 4;
    constexpr int ROWS = RSLOTS * R;
    constexpr int H = HC / 64;
    constexpr int XS = (HC == 128) ? 128 : 132;

    __shared__ float4 W_lds[128 * CG];
    __shared__ float x_lds[ROWS * XS];

    const int tid = threadIdx.x;
    const int cg = tid % CG;
    const int rslot = tid / CG;

    for (int i = tid; i < 128 * CG; i += 256)
        W_lds[i] = ((const float4*)W)[i];

    const float4 asv = ((const float4*)att_s)[cg];
    const float4 adv = ((const float4*)att_d)[cg];

    const int ntiles = (N + ROWS - 1) / ROWS;
    for (int t = blockIdx.x; t < ntiles; t += gridDim.x) {
        const int row0 = t * ROWS;
        __syncthreads();
        for (int i = tid; i < ROWS * 32; i += 256) {
            int r = i >> 5, k4 = i & 31;
            int row = row0 + r;
            float4 v = (row < N) ? ((const float4*)x)[(size_t)row * 32 + k4]
                                 : make_float4(0.f, 0.f, 0.f, 0.f);
            *(float4*)&x_lds[r * XS + k4 * 4] = v;
        }
        __syncthreads();

        float4 acc[R];
#pragma unroll
        for (int r = 0; r < R; ++r) acc[r] = make_float4(0.f, 0.f, 0.f, 0.f);

#pragma unroll 4
        for (int k = 0; k < 128; ++k) {
            float4 w = W_lds[k * CG + cg];
#pragma unroll
            for (int r = 0; r < R; ++r) {
                float xv = x_lds[(rslot * R + r) * XS + k];
                acc[r].x = fmaf(xv, w.x, acc[r].x);
                acc[r].y = fmaf(xv, w.y, acc[r].y);
                acc[r].z = fmaf(xv, w.z, acc[r].z);
                acc[r].w = fmaf(xv, w.w, acc[r].w);
            }
        }

#pragma unroll
        for (int r = 0; r < R; ++r) {
            int row = row0 + rslot * R + r;
            if (row < N) {
                __half2 p0 = __floats2half2_rn(acc[r].x, acc[r].y);
                __half2 p1 = __floats2half2_rn(acc[r].z, acc[r].w);
                uint2 pk;
                pk.x = *(unsigned*)&p0;
                pk.y = *(unsigned*)&p1;
                ((uint2*)h)[(size_t)row * CG + cg] = pk;
                float vs = acc[r].x * asv.x + acc[r].y * asv.y
                         + acc[r].z * asv.z + acc[r].w * asv.w;
                float vd = acc[r].x * adv.x + acc[r].y * adv.y
                         + acc[r].z * adv.z + acc[r].w * adv.w;
#pragma unroll
                for (int off = 1; off < 16; off <<= 1) {
                    vs += __shfl_xor(vs, off);
                    vd += __shfl_xor(vd, off);
                }
                if ((tid & 15) == 0) {
                    int head = (H == 2) ? ((tid >> 4) & 1) : 0;
                    a_s[row * H + head] = vs;
                    a_d[row * H + head] = vd;
                }
            }
        }
    }
}

// ---------------- CSR build via 2-level counting sort (bucket = dst>>8) ----
__global__ __launch_bounds__(256)
void bhist_k(const int* __restrict__ ei, int E, int Etot,
             int* __restrict__ bcnt, int nb) {
    __shared__ int lcnt[512];
    const int t = threadIdx.x;
    for (int i = t; i < nb; i += 256) lcnt[i] = 0;
    __syncthreads();
    const int c0 = blockIdx.x * CHUNK;
    const int lim = imin(CHUNK, Etot - c0);
    for (int j = t; j < lim; j += 256) {
        int e = c0 + j;
        int dst = (e < E) ? ei[E + e] : (e - E);
        atomicAdd(&lcnt[dst >> 8], 1);
    }
    __syncthreads();
    for (int i = t; i < nb; i += 256)
        if (lcnt[i]) atomicAdd(&bcnt[i], lcnt[i]);
}

__global__ __launch_bounds__(512)
void bscan_k(const int* __restrict__ bcnt, int* __restrict__ bbase,
             int* __restrict__ bnext, int* __restrict__ rowptr,
             int nb, int N, int Etot) {
    __shared__ int sm[512];
    int t = threadIdx.x;
    int v = (t < nb) ? bcnt[t] : 0;
    sm[t] = v; __syncthreads();
    for (int off = 1; off < 512; off <<= 1) {
        int u = (t >= off) ? sm[t - off] : 0;
        __syncthreads();
        sm[t] += u;
        __syncthreads();
    }
    if (t < nb) {
        int excl = sm[t] - v;
        bbase[t] = excl;
        bnext[t] = excl;
    }
    if (t == 0) {
        bbase[nb] = Etot;
        rowptr[N] = Etot;
    }
}

__global__ __launch_bounds__(256)
void bscatter_k(const int* __restrict__ ei, int E, int Etot,
                int* __restrict__ bnext, unsigned long long* __restrict__ pairs,
                int nb) {
    __shared__ int lcnt[512];
    __shared__ int lbase[512];
    const int t = threadIdx.x;
    const int c0 = blockIdx.x * CHUNK;
    const int lim = imin(CHUNK, Etot - c0);

    for (int i = t; i < nb; i += 256) lcnt[i] = 0;
    __syncthreads();
    for (int j = t; j < lim; j += 256) {
        int e = c0 + j;
        int dst = (e < E) ? ei[E + e] : (e - E);
        atomicAdd(&lcnt[dst >> 8], 1);
    }
    __syncthreads();
    for (int i = t; i < nb; i += 256) {
        int c = lcnt[i];
        lbase[i] = c ? atomicAdd(&bnext[i], c) : 0;
        lcnt[i] = 0;   // reuse as cursor
    }
    __syncthreads();
    for (int j = t; j < lim; j += 256) {
        int e = c0 + j;
        int src = (e < E) ? ei[e] : (e - E);
        int dst = (e < E) ? ei[E + e] : (e - E);
        int b = dst >> 8;
        int off = atomicAdd(&lcnt[b], 1);
        pairs[lbase[b] + off] = ((unsigned long long)(unsigned)dst << 32) | (unsigned)src;
    }
}

__global__ __launch_bounds__(256)
void fine_k(const unsigned long long* __restrict__ pairs,
            const int* __restrict__ bbase, int* __restrict__ rowptr,
            int* __restrict__ colsrc, int N) {
    __shared__ int sm[256];
    __shared__ int lnext[256];
    const int b = blockIdx.x, t = threadIdx.x;
    const int beg = bbase[b], end = bbase[b + 1];

    lnext[t] = 0;
    __syncthreads();
    for (int i = beg + t; i < end; i += 256)
        atomicAdd(&lnext[(int)(pairs[i] >> 32) & 255], 1);
    __syncthreads();
    int v = lnext[t];
    sm[t] = v; __syncthreads();
    for (int off = 1; off < 256; off <<= 1) {
        int u = (t >= off) ? sm[t - off] : 0;
        __syncthreads();
        sm[t] += u;
        __syncthreads();
    }
    int excl = sm[t] - v;
    int node = (b << 8) + t;
    if (node < N) rowptr[node] = beg + excl;
    lnext[t] = excl;
    __syncthreads();
    for (int i = beg + t; i < end; i += 256) {
        unsigned long long pr = pairs[i];
        int dst = (int)(pr >> 32);
        int src = (int)(pr & 0xffffffffu);
        int p = atomicAdd(&lnext[dst & 255], 1);
        colsrc[beg + p] = src;
    }
}

// ---------------- fused per-node aggregation, single-pass online softmax ----
// h gathered as fp16 (half the bytes of f32); all math in f32.
template<int H, bool ELU>
__global__ __launch_bounds__(256)
void node_aggr(const int* __restrict__ rowptr, const int* __restrict__ colsrc,
               const float* __restrict__ a_s, const float* __restrict__ a_d,
               const __half* __restrict__ h, const float* __restrict__ bias,
               float* __restrict__ out, int N) {
    int gw = (blockIdx.x * 256 + threadIdx.x) >> 6;
    int lane = threadIdx.x & 63;
    int nw = (gridDim.x * 256) >> 6;

    for (int n = gw; n < N; n += nw) {
        const int b = rowptr[n], deg = rowptr[n + 1] - b;

        if (H == 2) {
            const float2 adn = ((const float2*)a_d)[n];
            float m0 = -INFINITY, m1 = -INFINITY;
            float accx = 0.f, accy = 0.f, den = 0.f;
            for (int c = 0; c < deg; c += 64) {
                int ii = c + lane;
                int src_r = 0;
                float s0_r = -INFINITY, s1_r = -INFINITY;
                if (ii < deg) {
                    src_r = colsrc[b + ii];
                    float2 as = ((const float2*)a_s)[src_r];
                    s0_r = as.x + adn.x; s0_r = s0_r > 0.f ? s0_r : SLOPE * s0_r;
                    s1_r = as.y + adn.y; s1_r = s1_r > 0.f ? s1_r : SLOPE * s1_r;
                }
                float c0 = s0_r, c1 = s1_r;
#pragma unroll
                for (int off = 32; off; off >>= 1) {
                    c0 = fmaxf(c0, __shfl_xor(c0, off));
                    c1 = fmaxf(c1, __shfl_xor(c1, off));
                }
                float nm0 = fmaxf(m0, c0), nm1 = fmaxf(m1, c1);
                if (c > 0) {
                    float sc = (lane < 32) ? __expf(m0 - nm0) : __expf(m1 - nm1);
                    accx *= sc; accy *= sc; den *= sc;
                }
                m0 = nm0; m1 = nm1;
                float w0_r = __expf(s0_r - m0);
                float w1_r = __expf(s1_r - m1);
                int lim = (deg - c < 64) ? (deg - c) : 64;
#pragma unroll 2
                for (int i = 0; i < lim; ++i) {
                    int src = __shfl(src_r, i);
                    float w0b = __shfl(w0_r, i);
                    float w1b = __shfl(w1_r, i);
                    float w = (lane < 32) ? w0b : w1b;
                    den += w;
                    __half2 hh = ((const __half2*)h)[(size_t)src * 64 + lane];
                    float2 hv = __half22float2(hh);
                    accx = fmaf(w, hv.x, accx);
                    accy = fmaf(w, hv.y, accy);
                }
            }
            float2 bv = ((const float2*)bias)[lane];
            float vx = accx / den + bv.x;
            float vy = accy / den + bv.y;
            if (ELU) {
                vx = vx > 0.f ? vx : expm1f(vx);
                vy = vy > 0.f ? vy : expm1f(vy);
            }
            ((float2*)out)[(size_t)n * 64 + lane] = make_float2(vx, vy);
        } else {
            const float adn = a_d[n];
            float m = -INFINITY, acc = 0.f, den = 0.f;
            for (int c = 0; c < deg; c += 64) {
                int ii = c + lane;
                int src_r = 0;
                float s_r = -INFINITY;
                if (ii < deg) {
                    src_r = colsrc[b + ii];
                    s_r = a_s[src_r] + adn;
                    s_r = s_r > 0.f ? s_r : SLOPE * s_r;
                }
                float cm = s_r;
#pragma unroll
                for (int off = 32; off; off >>= 1) cm = fmaxf(cm, __shfl_xor(cm, off));
                float nm = fmaxf(m, cm);
                if (c > 0) {
                    float sc = __expf(m - nm);
                    acc *= sc; den *= sc;
                }
                m = nm;
                float w_r = __expf(s_r - m);
                int lim = (deg - c < 64) ? (deg - c) : 64;
#pragma unroll 2
                for (int i = 0; i < lim; ++i) {
                    int src = __shfl(src_r, i);
                    float w = __shfl(w_r, i);
                    den += w;
                    float hv = __half2float(h[(size_t)src * 64 + lane]);
                    acc = fmaf(w, hv, acc);
                }
            }
            float v = acc / den + bias[lane];
            if (ELU) v = v > 0.f ? v : expm1f(v);
            out[(size_t)n * 64 + lane] = v;
        }
    }
}

extern "C" void kernel_launch(void* const* d_in, const int* in_sizes, int n_in,
                              void* d_out, int out_size, void* d_ws, size_t ws_size,
                              hipStream_t stream) {
    const float* x   = (const float*)d_in[0];
    const int*   ei  = (const int*)d_in[1];
    const float* W1  = (const float*)d_in[2];
    const float* as1 = (const float*)d_in[3];
    const float* ad1 = (const float*)d_in[4];
    const float* b1  = (const float*)d_in[5];
    const float* W2  = (const float*)d_in[6];
    const float* as2 = (const float*)d_in[7];
    const float* ad2 = (const float*)d_in[8];
    const float* b2  = (const float*)d_in[9];
    float* out = (float*)d_out;

    const int N = out_size / 64;          // 100000
    const int E = in_sizes[1] / 2;        // 1600000
    const int Etot = E + N;               // + self loops
    const int nb = (N + 255) >> 8;        // buckets (391 <= 512)

    // workspace layout:
    // h1 region: 128N halves (25.6MB), aliased by pairs (u64 x Etot = 13.6MB) pre-gemm
    // h1e [128N f32] | a_s1 [2N] | a_d1 [2N] | a_s2 [N] | a_d2 [N] | ints
    float* ws   = (float*)d_ws;
    __half* h1  = (__half*)ws;                 // 128N halves = 64N floats
    float* h1e  = ws + (size_t)N * 64;
    float* a_s1 = h1e + (size_t)N * 128;
    float* a_d1 = a_s1 + (size_t)N * 2;
    float* a_s2 = a_d1 + (size_t)N * 2;
    float* a_d2 = a_s2 + (size_t)N;
    int* rowptr = (int*)(a_d2 + (size_t)N);
    int* bcnt   = rowptr + (N + 1);
    int* bbase  = bcnt + 512;
    int* bnext  = bbase + 513;
    int* colsrc = bnext + 512;
    unsigned long long* pairs = (unsigned long long*)h1;   // dead until gemm

    // ---- CSR build (shared by both layers) ----
    (void)hipMemsetAsync(bcnt, 0, (size_t)nb * 4, stream);
    int cb = (Etot + CHUNK - 1) / CHUNK;        // 416 chunks
    bhist_k<<<dim3(cb), dim3(256), 0, stream>>>(ei, E, Etot, bcnt, nb);
    bscan_k<<<dim3(1), dim3(512), 0, stream>>>(bcnt, bbase, bnext, rowptr, nb, N, Etot);
    bscatter_k<<<dim3(cb), dim3(256), 0, stream>>>(ei, E, Etot, bnext, pairs, nb);
    fine_k<<<dim3(nb), dim3(256), 0, stream>>>(pairs, bbase, rowptr, colsrc, N);

    int ab = imin((N + 3) / 4, 25000);

    // ---- layer 1 ----
    gemm_att<128><<<dim3(1024), dim3(256), 0, stream>>>(
        x, W1, as1, ad1, h1, a_s1, a_d1, N);
    node_aggr<2, true><<<dim3(ab), dim3(256), 0, stream>>>(
        rowptr, colsrc, a_s1, a_d1, h1, b1, h1e, N);

    // ---- layer 2 ----
    __half* h2 = h1;   // h1 dead after node_aggr<2>
    gemm_att<64><<<dim3(1024), dim3(256), 0, stream>>>(
        h1e, W2, as2, ad2, h2, a_s2, a_d2, N);
    node_aggr<1, false><<<dim3(ab), dim3(256), 0, stream>>>(
        rowptr, colsrc, a_s2, a_d2, h2, b2, out, N);
}

// Round 9
// 301.389 us; speedup vs baseline: 5.5523x; 1.3091x over previous
//
#include <hip/hip_runtime.h>
#include <hip/hip_bf16.h>
#include <hip/hip_fp16.h>
#include <math.h>

#define SLOPE 0.2f
#define CHUNK 4096

__host__ __device__ static inline int imin(int a, int b) { return a < b ? a : b; }

// ---------------- GEMM + attention dots; h written as fp16 ----------------
template<int HC>
__global__ __launch_bounds__(256, 2)
void gemm_att(const float* __restrict__ x, const float* __restrict__ W,
              const float* __restrict__ att_s, const float* __restrict__ att_d,
              __half* __restrict__ h, float* __restrict__ a_s, float* __restrict__ a_d,
              int N) {
    constexpr int CG = HC / 4;
    constexpr int RSLOTS = 256 / CG;
    constexpr int R = 4;
    constexpr int ROWS = RSLOTS * R;
    constexpr int H = HC / 64;
    constexpr int XS = (HC == 128) ? 128 : 132;

    __shared__ float4 W_lds[128 * CG];
    __shared__ float x_lds[ROWS * XS];

    const int tid = threadIdx.x;
    const int cg = tid % CG;
    const int rslot = tid / CG;

    for (int i = tid; i < 128 * CG; i += 256)
        W_lds[i] = ((const float4*)W)[i];

    const float4 asv = ((const float4*)att_s)[cg];
    const float4 adv = ((const float4*)att_d)[cg];

    const int ntiles = (N + ROWS - 1) / ROWS;
    for (int t = blockIdx.x; t < ntiles; t += gridDim.x) {
        const int row0 = t * ROWS;
        __syncthreads();
        for (int i = tid; i < ROWS * 32; i += 256) {
            int r = i >> 5, k4 = i & 31;
            int row = row0 + r;
            float4 v = (row < N) ? ((const float4*)x)[(size_t)row * 32 + k4]
                                 : make_float4(0.f, 0.f, 0.f, 0.f);
            *(float4*)&x_lds[r * XS + k4 * 4] = v;
        }
        __syncthreads();

        float4 acc[R];
#pragma unroll
        for (int r = 0; r < R; ++r) acc[r] = make_float4(0.f, 0.f, 0.f, 0.f);

#pragma unroll 4
        for (int k = 0; k < 128; ++k) {
            float4 w = W_lds[k * CG + cg];
#pragma unroll
            for (int r = 0; r < R; ++r) {
                float xv = x_lds[(rslot * R + r) * XS + k];
                acc[r].x = fmaf(xv, w.x, acc[r].x);
                acc[r].y = fmaf(xv, w.y, acc[r].y);
                acc[r].z = fmaf(xv, w.z, acc[r].z);
                acc[r].w = fmaf(xv, w.w, acc[r].w);
            }
        }

#pragma unroll
        for (int r = 0; r < R; ++r) {
            int row = row0 + rslot * R + r;
            if (row < N) {
                __half2 p0 = __floats2half2_rn(acc[r].x, acc[r].y);
                __half2 p1 = __floats2half2_rn(acc[r].z, acc[r].w);
                uint2 pk;
                pk.x = *(unsigned*)&p0;
                pk.y = *(unsigned*)&p1;
                ((uint2*)h)[(size_t)row * CG + cg] = pk;
                float vs = acc[r].x * asv.x + acc[r].y * asv.y
                         + acc[r].z * asv.z + acc[r].w * asv.w;
                float vd = acc[r].x * adv.x + acc[r].y * adv.y
                         + acc[r].z * adv.z + acc[r].w * adv.w;
#pragma unroll
                for (int off = 1; off < 16; off <<= 1) {
                    vs += __shfl_xor(vs, off);
                    vd += __shfl_xor(vd, off);
                }
                if ((tid & 15) == 0) {
                    int head = (H == 2) ? ((tid >> 4) & 1) : 0;
                    a_s[row * H + head] = vs;
                    a_d[row * H + head] = vd;
                }
            }
        }
    }
}

// ---------------- CSR build via 2-level counting sort (bucket = dst>>8) ----
__global__ __launch_bounds__(256)
void bhist_k(const int* __restrict__ ei, int E, int Etot,
             int* __restrict__ bcnt, int nb) {
    __shared__ int lcnt[512];
    const int t = threadIdx.x;
    for (int i = t; i < nb; i += 256) lcnt[i] = 0;
    __syncthreads();
    const int c0 = blockIdx.x * CHUNK;
    const int lim = imin(CHUNK, Etot - c0);
    for (int j = t; j < lim; j += 256) {
        int e = c0 + j;
        int dst = (e < E) ? ei[E + e] : (e - E);
        atomicAdd(&lcnt[dst >> 8], 1);
    }
    __syncthreads();
    for (int i = t; i < nb; i += 256)
        if (lcnt[i]) atomicAdd(&bcnt[i], lcnt[i]);
}

__global__ __launch_bounds__(512)
void bscan_k(const int* __restrict__ bcnt, int* __restrict__ bbase,
             int* __restrict__ bnext, int* __restrict__ rowptr,
             int nb, int N, int Etot) {
    __shared__ int sm[512];
    int t = threadIdx.x;
    int v = (t < nb) ? bcnt[t] : 0;
    sm[t] = v; __syncthreads();
    for (int off = 1; off < 512; off <<= 1) {
        int u = (t >= off) ? sm[t - off] : 0;
        __syncthreads();
        sm[t] += u;
        __syncthreads();
    }
    if (t < nb) {
        int excl = sm[t] - v;
        bbase[t] = excl;
        bnext[t] = excl;
    }
    if (t == 0) {
        bbase[nb] = Etot;
        rowptr[N] = Etot;
    }
}

__global__ __launch_bounds__(256)
void bscatter_k(const int* __restrict__ ei, int E, int Etot,
                int* __restrict__ bnext, unsigned long long* __restrict__ pairs,
                int nb) {
    __shared__ int lcnt[512];
    __shared__ int lbase[512];
    const int t = threadIdx.x;
    const int c0 = blockIdx.x * CHUNK;
    const int lim = imin(CHUNK, Etot - c0);

    for (int i = t; i < nb; i += 256) lcnt[i] = 0;
    __syncthreads();
    for (int j = t; j < lim; j += 256) {
        int e = c0 + j;
        int dst = (e < E) ? ei[E + e] : (e - E);
        atomicAdd(&lcnt[dst >> 8], 1);
    }
    __syncthreads();
    for (int i = t; i < nb; i += 256) {
        int c = lcnt[i];
        lbase[i] = c ? atomicAdd(&bnext[i], c) : 0;
        lcnt[i] = 0;   // reuse as cursor
    }
    __syncthreads();
    for (int j = t; j < lim; j += 256) {
        int e = c0 + j;
        int src = (e < E) ? ei[e] : (e - E);
        int dst = (e < E) ? ei[E + e] : (e - E);
        int b = dst >> 8;
        int off = atomicAdd(&lcnt[b], 1);
        pairs[lbase[b] + off] = ((unsigned long long)(unsigned)dst << 32) | (unsigned)src;
    }
}

__global__ __launch_bounds__(256)
void fine_k(const unsigned long long* __restrict__ pairs,
            const int* __restrict__ bbase, int* __restrict__ rowptr,
            int* __restrict__ colsrc, int N) {
    __shared__ int sm[256];
    __shared__ int lnext[256];
    const int b = blockIdx.x, t = threadIdx.x;
    const int beg = bbase[b], end = bbase[b + 1];

    lnext[t] = 0;
    __syncthreads();
    for (int i = beg + t; i < end; i += 256)
        atomicAdd(&lnext[(int)(pairs[i] >> 32) & 255], 1);
    __syncthreads();
    int v = lnext[t];
    sm[t] = v; __syncthreads();
    for (int off = 1; off < 256; off <<= 1) {
        int u = (t >= off) ? sm[t - off] : 0;
        __syncthreads();
        sm[t] += u;
        __syncthreads();
    }
    int excl = sm[t] - v;
    int node = (b << 8) + t;
    if (node < N) rowptr[node] = beg + excl;
    lnext[t] = excl;
    __syncthreads();
    for (int i = beg + t; i < end; i += 256) {
        unsigned long long pr = pairs[i];
        int dst = (int)(pr >> 32);
        int src = (int)(pr & 0xffffffffu);
        int p = atomicAdd(&lnext[dst & 255], 1);
        colsrc[beg + p] = src;
    }
}

// ---------------- per-node aggregation, edge-parallel lane groups ----------
// H=2: 4 groups x 16 lanes; each group processes one edge/iter, lane covers
// 8 channels (uint4 of fp16). Combine groups via shfl_xor(16,32) at the end.
template<bool ELU>
__global__ __launch_bounds__(256)
void node_aggr2(const int* __restrict__ rowptr, const int* __restrict__ colsrc,
                const float* __restrict__ a_s, const float* __restrict__ a_d,
                const __half* __restrict__ h, const float* __restrict__ bias,
                float* __restrict__ out, int N) {
    int gw = (blockIdx.x * 256 + threadIdx.x) >> 6;
    int lane = threadIdx.x & 63;
    int nw = (gridDim.x * 256) >> 6;
    const int g = lane >> 4;    // edge group
    const int p = lane & 15;    // channel slot: ch [p*8, p*8+8), head = p>>3
    float4 bv0 = ((const float4*)bias)[p * 2];
    float4 bv1 = ((const float4*)bias)[p * 2 + 1];

    for (int n = gw; n < N; n += nw) {
        const int b = rowptr[n], deg = rowptr[n + 1] - b;
        const float2 adn = ((const float2*)a_d)[n];
        float m0 = -INFINITY, m1 = -INFINITY;
        float4 acc0 = make_float4(0.f, 0.f, 0.f, 0.f);
        float4 acc1 = make_float4(0.f, 0.f, 0.f, 0.f);
        float den = 0.f;

        for (int c = 0; c < deg; c += 64) {
            int ii = c + lane;
            int src_r = 0;
            float s0_r = -INFINITY, s1_r = -INFINITY;
            if (ii < deg) {
                src_r = colsrc[b + ii];
                float2 as = ((const float2*)a_s)[src_r];
                s0_r = as.x + adn.x; s0_r = s0_r > 0.f ? s0_r : SLOPE * s0_r;
                s1_r = as.y + adn.y; s1_r = s1_r > 0.f ? s1_r : SLOPE * s1_r;
            }
            float c0 = s0_r, c1 = s1_r;
#pragma unroll
            for (int off = 32; off; off >>= 1) {
                c0 = fmaxf(c0, __shfl_xor(c0, off));
                c1 = fmaxf(c1, __shfl_xor(c1, off));
            }
            float nm0 = fmaxf(m0, c0), nm1 = fmaxf(m1, c1);
            if (c > 0) {
                float sc = (p < 8) ? __expf(m0 - nm0) : __expf(m1 - nm1);
                acc0.x *= sc; acc0.y *= sc; acc0.z *= sc; acc0.w *= sc;
                acc1.x *= sc; acc1.y *= sc; acc1.z *= sc; acc1.w *= sc;
                den *= sc;
            }
            m0 = nm0; m1 = nm1;
            float w0_r = __expf(s0_r - m0);   // 0 for inactive lanes
            float w1_r = __expf(s1_r - m1);
            int lim = (deg - c < 64) ? (deg - c) : 64;
#pragma unroll 2
            for (int i = 0; i < lim; i += 4) {
                int e = i + g;                 // this group's edge (w=0 if >= lim)
                int src = __shfl(src_r, e);
                float w0b = __shfl(w0_r, e);
                float w1b = __shfl(w1_r, e);
                float w = (p < 8) ? w0b : w1b;
                den += w;
                uint4 hv = ((const uint4*)h)[(size_t)src * 16 + p];
                float2 f0 = __half22float2(*(__half2*)&hv.x);
                float2 f1 = __half22float2(*(__half2*)&hv.y);
                float2 f2 = __half22float2(*(__half2*)&hv.z);
                float2 f3 = __half22float2(*(__half2*)&hv.w);
                acc0.x = fmaf(w, f0.x, acc0.x); acc0.y = fmaf(w, f0.y, acc0.y);
                acc0.z = fmaf(w, f1.x, acc0.z); acc0.w = fmaf(w, f1.y, acc0.w);
                acc1.x = fmaf(w, f2.x, acc1.x); acc1.y = fmaf(w, f2.y, acc1.y);
                acc1.z = fmaf(w, f3.x, acc1.z); acc1.w = fmaf(w, f3.y, acc1.w);
            }
        }
        // combine the 4 edge-groups (lane bits 4,5)
#pragma unroll
        for (int off = 16; off <= 32; off <<= 1) {
            acc0.x += __shfl_xor(acc0.x, off); acc0.y += __shfl_xor(acc0.y, off);
            acc0.z += __shfl_xor(acc0.z, off); acc0.w += __shfl_xor(acc0.w, off);
            acc1.x += __shfl_xor(acc1.x, off); acc1.y += __shfl_xor(acc1.y, off);
            acc1.z += __shfl_xor(acc1.z, off); acc1.w += __shfl_xor(acc1.w, off);
            den    += __shfl_xor(den, off);
        }
        if (lane < 16) {
            float inv = 1.f / den;
            float4 o0, o1;
            o0.x = acc0.x * inv + bv0.x; o0.y = acc0.y * inv + bv0.y;
            o0.z = acc0.z * inv + bv0.z; o0.w = acc0.w * inv + bv0.w;
            o1.x = acc1.x * inv + bv1.x; o1.y = acc1.y * inv + bv1.y;
            o1.z = acc1.z * inv + bv1.z; o1.w = acc1.w * inv + bv1.w;
            if (ELU) {
                o0.x = o0.x > 0.f ? o0.x : expm1f(o0.x);
                o0.y = o0.y > 0.f ? o0.y : expm1f(o0.y);
                o0.z = o0.z > 0.f ? o0.z : expm1f(o0.z);
                o0.w = o0.w > 0.f ? o0.w : expm1f(o0.w);
                o1.x = o1.x > 0.f ? o1.x : expm1f(o1.x);
                o1.y = o1.y > 0.f ? o1.y : expm1f(o1.y);
                o1.z = o1.z > 0.f ? o1.z : expm1f(o1.z);
                o1.w = o1.w > 0.f ? o1.w : expm1f(o1.w);
            }
            ((float4*)out)[(size_t)n * 32 + p * 2]     = o0;
            ((float4*)out)[(size_t)n * 32 + p * 2 + 1] = o1;
        }
    }
}

// H=1: 8 groups x 8 lanes; 8 edges/iter; combine via shfl_xor(8,16,32).
__global__ __launch_bounds__(256)
void node_aggr1(const int* __restrict__ rowptr, const int* __restrict__ colsrc,
                const float* __restrict__ a_s, const float* __restrict__ a_d,
                const __half* __restrict__ h, const float* __restrict__ bias,
                float* __restrict__ out, int N) {
    int gw = (blockIdx.x * 256 + threadIdx.x) >> 6;
    int lane = threadIdx.x & 63;
    int nw = (gridDim.x * 256) >> 6;
    const int g = lane >> 3;    // edge group
    const int p = lane & 7;     // channel slot: ch [p*8, p*8+8)
    float4 bv0 = ((const float4*)bias)[p * 2];
    float4 bv1 = ((const float4*)bias)[p * 2 + 1];

    for (int n = gw; n < N; n += nw) {
        const int b = rowptr[n], deg = rowptr[n + 1] - b;
        const float adn = a_d[n];
        float m = -INFINITY, den = 0.f;
        float4 acc0 = make_float4(0.f, 0.f, 0.f, 0.f);
        float4 acc1 = make_float4(0.f, 0.f, 0.f, 0.f);

        for (int c = 0; c < deg; c += 64) {
            int ii = c + lane;
            int src_r = 0;
            float s_r = -INFINITY;
            if (ii < deg) {
                src_r = colsrc[b + ii];
                s_r = a_s[src_r] + adn;
                s_r = s_r > 0.f ? s_r : SLOPE * s_r;
            }
            float cm = s_r;
#pragma unroll
            for (int off = 32; off; off >>= 1) cm = fmaxf(cm, __shfl_xor(cm, off));
            float nm = fmaxf(m, cm);
            if (c > 0) {
                float sc = __expf(m - nm);
                acc0.x *= sc; acc0.y *= sc; acc0.z *= sc; acc0.w *= sc;
                acc1.x *= sc; acc1.y *= sc; acc1.z *= sc; acc1.w *= sc;
                den *= sc;
            }
            m = nm;
            float w_r = __expf(s_r - m);
            int lim = (deg - c < 64) ? (deg - c) : 64;
#pragma unroll 2
            for (int i = 0; i < lim; i += 8) {
                int e = i + g;
                int src = __shfl(src_r, e);
                float w = __shfl(w_r, e);
                den += w;
                uint4 hv = ((const uint4*)h)[(size_t)src * 8 + p];
                float2 f0 = __half22float2(*(__half2*)&hv.x);
                float2 f1 = __half22float2(*(__half2*)&hv.y);
                float2 f2 = __half22float2(*(__half2*)&hv.z);
                float2 f3 = __half22float2(*(__half2*)&hv.w);
                acc0.x = fmaf(w, f0.x, acc0.x); acc0.y = fmaf(w, f0.y, acc0.y);
                acc0.z = fmaf(w, f1.x, acc0.z); acc0.w = fmaf(w, f1.y, acc0.w);
                acc1.x = fmaf(w, f2.x, acc1.x); acc1.y = fmaf(w, f2.y, acc1.y);
                acc1.z = fmaf(w, f3.x, acc1.z); acc1.w = fmaf(w, f3.y, acc1.w);
            }
        }
#pragma unroll
        for (int off = 8; off <= 32; off <<= 1) {
            acc0.x += __shfl_xor(acc0.x, off); acc0.y += __shfl_xor(acc0.y, off);
            acc0.z += __shfl_xor(acc0.z, off); acc0.w += __shfl_xor(acc0.w, off);
            acc1.x += __shfl_xor(acc1.x, off); acc1.y += __shfl_xor(acc1.y, off);
            acc1.z += __shfl_xor(acc1.z, off); acc1.w += __shfl_xor(acc1.w, off);
            den    += __shfl_xor(den, off);
        }
        if (lane < 8) {
            float inv = 1.f / den;
            float4 o0, o1;
            o0.x = acc0.x * inv + bv0.x; o0.y = acc0.y * inv + bv0.y;
            o0.z = acc0.z * inv + bv0.z; o0.w = acc0.w * inv + bv0.w;
            o1.x = acc1.x * inv + bv1.x; o1.y = acc1.y * inv + bv1.y;
            o1.z = acc1.z * inv + bv1.z; o1.w = acc1.w * inv + bv1.w;
            ((float4*)out)[(size_t)n * 16 + p * 2]     = o0;
            ((float4*)out)[(size_t)n * 16 + p * 2 + 1] = o1;
        }
    }
}

extern "C" void kernel_launch(void* const* d_in, const int* in_sizes, int n_in,
                              void* d_out, int out_size, void* d_ws, size_t ws_size,
                              hipStream_t stream) {
    const float* x   = (const float*)d_in[0];
    const int*   ei  = (const int*)d_in[1];
    const float* W1  = (const float*)d_in[2];
    const float* as1 = (const float*)d_in[3];
    const float* ad1 = (const float*)d_in[4];
    const float* b1  = (const float*)d_in[5];
    const float* W2  = (const float*)d_in[6];
    const float* as2 = (const float*)d_in[7];
    const float* ad2 = (const float*)d_in[8];
    const float* b2  = (const float*)d_in[9];
    float* out = (float*)d_out;

    const int N = out_size / 64;          // 100000
    const int E = in_sizes[1] / 2;        // 1600000
    const int Etot = E + N;               // + self loops
    const int nb = (N + 255) >> 8;        // buckets (391 <= 512)

    float* ws   = (float*)d_ws;
    __half* h1  = (__half*)ws;                 // 128N halves = 64N floats
    float* h1e  = ws + (size_t)N * 64;
    float* a_s1 = h1e + (size_t)N * 128;
    float* a_d1 = a_s1 + (size_t)N * 2;
    float* a_s2 = a_d1 + (size_t)N * 2;
    float* a_d2 = a_s2 + (size_t)N;
    int* rowptr = (int*)(a_d2 + (size_t)N);
    int* bcnt   = rowptr + (N + 1);
    int* bbase  = bcnt + 512;
    int* bnext  = bbase + 513;
    int* colsrc = bnext + 512;
    unsigned long long* pairs = (unsigned long long*)h1;   // dead until gemm

    // ---- CSR build (shared by both layers) ----
    (void)hipMemsetAsync(bcnt, 0, (size_t)nb * 4, stream);
    int cb = (Etot + CHUNK - 1) / CHUNK;        // 416 chunks
    bhist_k<<<dim3(cb), dim3(256), 0, stream>>>(ei, E, Etot, bcnt, nb);
    bscan_k<<<dim3(1), dim3(512), 0, stream>>>(bcnt, bbase, bnext, rowptr, nb, N, Etot);
    bscatter_k<<<dim3(cb), dim3(256), 0, stream>>>(ei, E, Etot, bnext, pairs, nb);
    fine_k<<<dim3(nb), dim3(256), 0, stream>>>(pairs, bbase, rowptr, colsrc, N);

    int ab = imin((N + 3) / 4, 25000);

    // ---- layer 1 ----
    gemm_att<128><<<dim3(1024), dim3(256), 0, stream>>>(
        x, W1, as1, ad1, h1, a_s1, a_d1, N);
    node_aggr2<true><<<dim3(ab), dim3(256), 0, stream>>>(
        rowptr, colsrc, a_s1, a_d1, h1, b1, h1e, N);

    // ---- layer 2 ----
    __half* h2 = h1;   // h1 dead after node_aggr2
    gemm_att<64><<<dim3(1024), dim3(256), 0, stream>>>(
        h1e, W2, as2, ad2, h2, a_s2, a_d2, N);
    node_aggr1<<<dim3(ab), dim3(256), 0, stream>>>(
        rowptr, colsrc, a_s2, a_d2, h2, b2, out, N);
}